// Round 6
// baseline (190.735 us; speedup 1.0000x reference)
//
#include <hip/hip_runtime.h>
#include <hip/hip_bf16.h>
#include <stdint.h>

typedef __attribute__((ext_vector_type(8))) short short8;
typedef __attribute__((ext_vector_type(4))) float f32x4;
typedef __attribute__((ext_vector_type(16))) float f32x16;

#define AS1 __attribute__((address_space(1)))
#define AS3 __attribute__((address_space(3)))

constexpr int Bc = 4, Sc = 2048, Dc = 1024, Hc = 16;

__device__ __forceinline__ unsigned short f2b(float x) {
  __hip_bfloat16 h = __float2bfloat16(x);
  return *reinterpret_cast<unsigned short*>(&h);
}

__device__ __forceinline__ uint32_t cvtpk(float lo, float hi) {
  uint32_t r;
  asm("v_cvt_pk_bf16_f32 %0, %1, %2" : "=v"(r) : "v"(lo), "v"(hi));
  return r;
}

// async global->LDS, 16B per lane; lds ptr must be wave-uniform (HW adds lane*16)
__device__ __forceinline__ void glds16(const void* g, void* l) {
  __builtin_amdgcn_global_load_lds((const AS1 uint32_t*)g, (AS3 uint32_t*)l, 16, 0, 0);
}

// ---------------------------------------------------------------- cast kernels
__global__ void cast_f32_bf16_x4(const float* __restrict__ in,
                                 unsigned short* __restrict__ out, int n4) {
  int i = blockIdx.x * blockDim.x + threadIdx.x;
  if (i >= n4) return;
  float4 a = ((const float4*)in)[i];
  ushort4 o;
  o.x = f2b(a.x); o.y = f2b(a.y); o.z = f2b(a.z); o.w = f2b(a.w);
  ((ushort4*)out)[i] = o;
}

// all four 1024x1024 weights in one launch: grid (1024, 4)
__global__ void cast_w4(const float* __restrict__ wq, const float* __restrict__ wk,
                        const float* __restrict__ wv, const float* __restrict__ wo,
                        unsigned short* __restrict__ oq, unsigned short* __restrict__ ok,
                        unsigned short* __restrict__ ov, unsigned short* __restrict__ oo) {
  int which = blockIdx.y;
  const float* in = which == 0 ? wq : which == 1 ? wk : which == 2 ? wv : wo;
  unsigned short* out = which == 0 ? oq : which == 1 ? ok : which == 2 ? ov : oo;
  int i = blockIdx.x * blockDim.x + threadIdx.x;
  float4 a = ((const float4*)in)[i];
  ushort4 o;
  o.x = f2b(a.x); o.y = f2b(a.y); o.z = f2b(a.z); o.w = f2b(a.w);
  ((ushort4*)out)[i] = o;
}

// ------------------------------------------------------- 128x128 GEMM core
// C[M,N] = A[M,K] * W[N,K]^T + bias;  K = N = 1024 fixed, tile 128x128, BK=32.
// Double-buffered LDS with the K-loop UNROLLED x2 (compile-time buf ->
// ds_read offset:imm, no runtime LDS indexing). Incremental global pointers
// (+32 elem/tile). Schedule per tile: stage(next,other buf) -> ds_read+MFMA(cur)
// -> vmcnt(0)+s_barrier (single barrier per tile; reads are lgkm-drained
// before MFMA issue, so retired before the barrier).
// Chunk-XOR swizzle slot = g ^ ((row>>1)&3) via pre-swizzled global source.
template<int MODE>
__device__ __forceinline__ void gemm128(
    const unsigned short* __restrict__ A, const unsigned short* __restrict__ W,
    const float* __restrict__ bias, void* __restrict__ outp,
    int m0, int n0, unsigned short (*lA)[128 * 32], unsigned short (*lB)[128 * 32])
{
  const int tid = threadIdx.x;
  const int w = tid >> 6, lane = tid & 63;
  const int g = lane >> 4, c = lane & 15;
  const int wr = w >> 1, wc = w & 1;

  f32x4 acc[4][4];
#pragma unroll
  for (int i = 0; i < 4; ++i)
#pragma unroll
    for (int j = 0; j < 4; ++j) acc[i][j] = f32x4{0.f, 0.f, 0.f, 0.f};

  const int srow = lane >> 2;                       // 0..15 local row
  const int gch = (lane & 3) ^ ((srow >> 1) & 3);   // pre-swizzled source chunk
  const int rslot = (g ^ ((c >> 1) & 3)) * 16;      // read-side byte slot

  // incremental per-lane global pointers (advance 32 elems per tile)
  const unsigned short* a0 = A + (size_t)(m0 + w * 16 + srow) * 1024 + gch * 8;
  const unsigned short* a1 = a0 + 64 * 1024;
  const unsigned short* b0 = W + (size_t)(n0 + w * 16 + srow) * 1024 + gch * 8;
  const unsigned short* b1 = b0 + 64 * 1024;

#define STAGE(buf)                                           \
  do {                                                       \
    glds16(a0, (char*)lA[buf] + w * 1024);                   \
    glds16(a1, (char*)lA[buf] + 4096 + w * 1024);            \
    glds16(b0, (char*)lB[buf] + w * 1024);                   \
    glds16(b1, (char*)lB[buf] + 4096 + w * 1024);            \
    a0 += 32; a1 += 32; b0 += 32; b1 += 32;                  \
  } while (0)

#define COMPUTE(buf)                                                          \
  do {                                                                        \
    short8 aF[4], bF[4];                                                      \
    _Pragma("unroll")                                                         \
    for (int mt = 0; mt < 4; ++mt)                                            \
      aF[mt] = *(const short8*)((const char*)lA[buf] +                        \
                 (wr * 64 + mt * 16 + c) * 64 + rslot);                       \
    _Pragma("unroll")                                                         \
    for (int nt = 0; nt < 4; ++nt)                                            \
      bF[nt] = *(const short8*)((const char*)lB[buf] +                        \
                 (wc * 64 + nt * 16 + c) * 64 + rslot);                       \
    _Pragma("unroll")                                                         \
    for (int mt = 0; mt < 4; ++mt)                                            \
      _Pragma("unroll")                                                       \
      for (int nt = 0; nt < 4; ++nt)                                          \
        acc[mt][nt] = __builtin_amdgcn_mfma_f32_16x16x32_bf16(                \
            aF[mt], bF[nt], acc[mt][nt], 0, 0, 0);                            \
  } while (0)

#define TILE_END                                     \
  do {                                               \
    asm volatile("s_waitcnt vmcnt(0)" ::: "memory"); \
    __builtin_amdgcn_s_barrier();                    \
    asm volatile("" ::: "memory");                   \
  } while (0)

  STAGE(0);
  for (int t2 = 0; t2 < 32; t2 += 2) {
    // tile t2 (buf0); stage t2+1 -> buf1 (t2+1 <= 31 always)
    STAGE(1);
    COMPUTE(0);
    TILE_END;
    // tile t2+1 (buf1); stage t2+2 -> buf0 if it exists
    if (t2 + 2 < 32) STAGE(0);
    COMPUTE(1);
    TILE_END;
  }
#undef STAGE
#undef COMPUTE
#undef TILE_END

  // epilogue: C row = 4g+reg, col = c (per 16x16 tile)
#pragma unroll
  for (int mt = 0; mt < 4; ++mt) {
    int mg = m0 + wr * 64 + mt * 16 + 4 * g;
#pragma unroll
    for (int nt = 0; nt < 4; ++nt) {
      int ng = n0 + wc * 64 + nt * 16 + c;
      float bb_ = bias[ng];
      if constexpr (MODE == 0) {
        unsigned short* o = (unsigned short*)outp;
#pragma unroll
        for (int r = 0; r < 4; ++r)
          o[(size_t)(mg + r) * 1024 + ng] = f2b(acc[mt][nt][r] + bb_);
      } else if constexpr (MODE == 1) {
        unsigned short* o = (unsigned short*)outp;
        int bb = mg >> 11, s0 = mg & 2047;   // batch, seq (tile never crosses batch)
        int hh = ng >> 6, dd = ng & 63;      // head, depth
        ushort4 pk;
        pk.x = f2b(acc[mt][nt][0] + bb_);
        pk.y = f2b(acc[mt][nt][1] + bb_);
        pk.z = f2b(acc[mt][nt][2] + bb_);
        pk.w = f2b(acc[mt][nt][3] + bb_);
        *(ushort4*)&o[(((size_t)bb * Hc + hh) * 64 + dd) * Sc + s0] = pk;
      } else {
        float* o = (float*)outp;
#pragma unroll
        for (int r = 0; r < 4; ++r)
          o[(size_t)(mg + r) * 1024 + ng] = acc[mt][nt][r] + bb_;
      }
    }
  }
}

__global__ __launch_bounds__(256) void qkv_gemm(
    const unsigned short* __restrict__ xb,
    const unsigned short* __restrict__ wqb, const unsigned short* __restrict__ wkb,
    const unsigned short* __restrict__ wvb,
    const float* __restrict__ bq, const float* __restrict__ bk,
    const float* __restrict__ bv,
    unsigned short* __restrict__ qo, unsigned short* __restrict__ ko,
    unsigned short* __restrict__ vto)
{
  __shared__ unsigned short lA[2][128 * 32], lB[2][128 * 32];
  int which = blockIdx.x >> 3;
  int n0 = (blockIdx.x & 7) * 128;
  int m0 = blockIdx.y * 128;
  if (which == 0)      gemm128<0>(xb, wqb, bq, qo, m0, n0, lA, lB);
  else if (which == 1) gemm128<0>(xb, wkb, bk, ko, m0, n0, lA, lB);
  else                 gemm128<1>(xb, wvb, bv, vto, m0, n0, lA, lB);
}

__global__ __launch_bounds__(256) void out_gemm(
    const unsigned short* __restrict__ ao, const unsigned short* __restrict__ wob,
    const float* __restrict__ bo, float* __restrict__ out)
{
  __shared__ unsigned short lA[2][128 * 32], lB[2][128 * 32];
  gemm128<2>(ao, wob, bo, out, blockIdx.y * 128, blockIdx.x * 128, lA, lB);
}

// ----------------------------------------------------------- flash attention
// Paired q-tiles (qlo=y, qhi=15-y) sharing K/V staging; same-bh blocks on the
// same XCD. 32x32x16 MFMA, SWAPPED operands (T12): S^T = mfma(K,Q) so each
// lane owns one q-row (q = lane&31); softmax is in-lane + one shfl_xor(32).
// P^T stays in-register: cvt_pk -> xor-32 exchange -> B-operand of
// O^T = mfma(V^T, P^T). No P-LDS, no lgkm drains. LDS 32KB.
__global__ __launch_bounds__(256, 2) void attn_kernel(
    const unsigned short* __restrict__ qg, const unsigned short* __restrict__ kg,
    const unsigned short* __restrict__ vtg, unsigned short* __restrict__ ao)
{
  __shared__ unsigned short lK[2][64 * 64];
  __shared__ unsigned short lV[2][64 * 64];

  const int bh = blockIdx.x;
  const int qlo = blockIdx.y, qhi = 15 - qlo;
  const int b = bh >> 4, h = bh & 15;
  const int tid = threadIdx.x, w = tid >> 6, lane = tid & 63;
  const int qr = lane & 31, hi = lane >> 5;
  const int qb2[2] = { qlo * 128 + 32 * w, qhi * 128 + 32 * w };
  constexpr float CE = 0.125f * 1.44269504f;   // fold /sqrt(64) and log2(e)

  // Q as B-operand: col=q=qr, k(d) = 16i + 8hi + j
  short8 qB[2][4];
#pragma unroll
  for (int qi = 0; qi < 2; ++qi) {
    const unsigned short* qp = qg + (size_t)(b * Sc + qb2[qi] + qr) * Dc + h * 64 + 8 * hi;
#pragma unroll
    for (int i = 0; i < 4; ++i)
      qB[qi][i] = *(const short8*)(qp + 16 * i);
  }

  float m_[2] = { -3e38f, -3e38f }, lv[2] = { 0.f, 0.f };
  f32x16 oT[2][2];
#pragma unroll
  for (int qi = 0; qi < 2; ++qi)
#pragma unroll
    for (int n = 0; n < 2; ++n)
#pragma unroll
      for (int r = 0; r < 16; ++r) oT[qi][n][r] = 0.f;

  const int srow8 = lane >> 3;
  const int sslot = lane & 7;
  const unsigned short* kb_ = kg + (size_t)b * Sc * Dc + h * 64;
  const unsigned short* vb_ = vtg + (size_t)bh * 64 * Sc;

  auto stage = [&](int buf, int t) {
    const int kv0 = t * 64;
#pragma unroll
    for (int i = 0; i < 2; ++i) {
      int row = i * 32 + w * 8 + srow8;
      int gch = sslot ^ (row & 7);
      glds16(kb_ + (size_t)(kv0 + row) * Dc + gch * 8,
             (char*)lK[buf] + i * 4096 + w * 1024);
      glds16(vb_ + (size_t)row * Sc + kv0 + gch * 8,
             (char*)lV[buf] + i * 4096 + w * 1024);
    }
  };

  const int ntl = 2 * (qhi + 1);
  stage(0, 0);
  asm volatile("s_waitcnt vmcnt(0)" ::: "memory");
  __builtin_amdgcn_s_barrier();
  asm volatile("" ::: "memory");

  for (int t = 0; t < ntl; ++t) {
    const int cur = t & 1;
    const int kv0 = t * 64;
    if (t + 1 < ntl) stage(cur ^ 1, t + 1);

    if (kv0 <= qb2[1] + 31) {   // at least qhi active (wave-uniform)
      // K as A-operand (shared by both q-tiles): row=k-idx, d-chunk 2i+hi
      short8 kA[2][4];
#pragma unroll
      for (int kblk = 0; kblk < 2; ++kblk) {
        const int row = kblk * 32 + qr;
        const int swz = (row & 7) << 4;
#pragma unroll
        for (int i = 0; i < 4; ++i)
          kA[kblk][i] = *(const short8*)((const char*)lK[cur] + row * 128 +
                          (((2 * i + hi) * 16) ^ swz));
      }

      short8 pB[2][4];        // P^T B-frags per q-tile
      bool act[2];
#pragma unroll
      for (int qi = 0; qi < 2; ++qi) {
        const int qbase = qb2[qi];
        act[qi] = (kv0 <= qbase + 31);
        if (!act[qi]) continue;

        // ---- S^T = K Q (32k x 32q per block, 2 k-blocks)
        f32x16 sT[2];
        __builtin_amdgcn_s_setprio(1);
#pragma unroll
        for (int kblk = 0; kblk < 2; ++kblk) {
          f32x16 s;
#pragma unroll
          for (int r = 0; r < 16; ++r) s[r] = 0.f;
#pragma unroll
          for (int i = 0; i < 4; ++i)
            s = __builtin_amdgcn_mfma_f32_32x32x16_bf16(kA[kblk][i], qB[qi][i],
                                                        s, 0, 0, 0);
          sT[kblk] = s;
        }
        __builtin_amdgcn_s_setprio(0);

        // ---- causal mask (partial tiles only); q=qbase+qr, k from C-layout
        if (kv0 + 63 > qbase) {
          const int q = qbase + qr;
#pragma unroll
          for (int kblk = 0; kblk < 2; ++kblk)
#pragma unroll
            for (int r = 0; r < 16; ++r) {
              int k = kv0 + kblk * 32 + (r & 3) + 8 * (r >> 2) + 4 * hi;
              if (k > q) sT[kblk][r] = -1e30f;
            }
        }

        // ---- online softmax, in-lane + one xor-32 exchange
        float mx = sT[0][0];
#pragma unroll
        for (int r = 1; r < 16; ++r) mx = fmaxf(mx, sT[0][r]);
#pragma unroll
        for (int r = 0; r < 16; ++r) mx = fmaxf(mx, sT[1][r]);
        mx = fmaxf(mx, __shfl_xor(mx, 32));

        if (!__all(mx <= m_[qi] + 64.f)) {   // T13 defer-rescale (8 ln-units)
          const float mo = m_[qi];
          const float mn = fmaxf(mo, mx);
          const float sf = __builtin_amdgcn_exp2f((mo - mn) * CE);
          m_[qi] = mn;
          lv[qi] *= sf;
#pragma unroll
          for (int n = 0; n < 2; ++n)
#pragma unroll
            for (int r = 0; r < 16; ++r) oT[qi][n][r] *= sf;
        }
        const float mc = m_[qi] * CE;
        float ls = 0.f;
#pragma unroll
        for (int kblk = 0; kblk < 2; ++kblk)
#pragma unroll
          for (int r = 0; r < 16; ++r) {
            float p = __builtin_amdgcn_exp2f(sT[kblk][r] * CE - mc);
            sT[kblk][r] = p;
            ls += p;
          }
        lv[qi] += ls;    // per-lane partial; xor-32 reduce at end

        // ---- P^T -> bf16 B-frags, in-register exchange across xor-32
#pragma unroll
        for (int kblk = 0; kblk < 2; ++kblk) {
          uint32_t pk[4][2];
#pragma unroll
          for (int qp = 0; qp < 4; ++qp)
#pragma unroll
            for (int rp = 0; rp < 2; ++rp)
              pk[qp][rp] = cvtpk(sT[kblk][4 * qp + 2 * rp],
                                 sT[kblk][4 * qp + 2 * rp + 1]);
#pragma unroll
          for (int m2 = 0; m2 < 2; ++m2) {
            uint32_t s0 = hi ? pk[2 * m2][0] : pk[2 * m2 + 1][0];
            uint32_t s1 = hi ? pk[2 * m2][1] : pk[2 * m2 + 1][1];
            uint32_t r0 = __shfl_xor(s0, 32);
            uint32_t r1 = __shfl_xor(s1, 32);
            uint32_t w0 = hi ? r0 : pk[2 * m2][0];
            uint32_t w1 = hi ? r1 : pk[2 * m2][1];
            uint32_t w2 = hi ? pk[2 * m2 + 1][0] : r0;
            uint32_t w3 = hi ? pk[2 * m2 + 1][1] : r1;
            uint32_t tmp[4] = { w0, w1, w2, w3 };
            pB[qi][2 * kblk + m2] = *(const short8*)tmp;
          }
        }
      }

      // V^T as A-operand (shared): row=d, kv-chunk 2m+hi
      short8 vA[2][4];
#pragma unroll
      for (int n = 0; n < 2; ++n) {
        const int row = 32 * n + qr;
        const int swz = (row & 7) << 4;
#pragma unroll
        for (int m = 0; m < 4; ++m)
          vA[n][m] = *(const short8*)((const char*)lV[cur] + row * 128 +
                       (((2 * m + hi) * 16) ^ swz));
      }

      // ---- O^T += V^T P^T
      __builtin_amdgcn_s_setprio(1);
#pragma unroll
      for (int qi = 0; qi < 2; ++qi) {
        if (!act[qi]) continue;
#pragma unroll
        for (int n = 0; n < 2; ++n)
#pragma unroll
          for (int m = 0; m < 4; ++m)
            oT[qi][n] = __builtin_amdgcn_mfma_f32_32x32x16_bf16(
                vA[n][m], pB[qi][m], oT[qi][n], 0, 0, 0);
      }
      __builtin_amdgcn_s_setprio(0);
    }

    asm volatile("s_waitcnt vmcnt(0)" ::: "memory");
    __builtin_amdgcn_s_barrier();
    asm volatile("" ::: "memory");
  }

  // ---- finalize: full row-sum via xor-32, normalize, packed store
#pragma unroll
  for (int qi = 0; qi < 2; ++qi) {
    float l = lv[qi] + __shfl_xor(lv[qi], 32);
    float inv = 1.0f / l;
    const int qrow = qb2[qi] + qr;
    unsigned short* op = ao + (size_t)(b * Sc + qrow) * Dc + h * 64;
#pragma unroll
    for (int n = 0; n < 2; ++n)
#pragma unroll
      for (int rg = 0; rg < 4; ++rg) {
        ushort4 pkv;
        pkv.x = f2b(oT[qi][n][4 * rg + 0] * inv);
        pkv.y = f2b(oT[qi][n][4 * rg + 1] * inv);
        pkv.z = f2b(oT[qi][n][4 * rg + 2] * inv);
        pkv.w = f2b(oT[qi][n][4 * rg + 3] * inv);
        *(ushort4*)(op + 32 * n + 8 * rg + 4 * hi) = pkv;
      }
  }
}

// ------------------------------------------------------------------- launch
extern "C" void kernel_launch(void* const* d_in, const int* in_sizes, int n_in,
                              void* d_out, int out_size, void* d_ws, size_t ws_size,
                              hipStream_t stream) {
  const float* x  = (const float*)d_in[0];
  // d_in[1] = mask: causal triu(k=1), applied analytically in attn_kernel
  const float* wq = (const float*)d_in[2];
  const float* bq = (const float*)d_in[3];
  const float* wk = (const float*)d_in[4];
  const float* bk = (const float*)d_in[5];
  const float* wv = (const float*)d_in[6];
  const float* bv = (const float*)d_in[7];
  const float* wo = (const float*)d_in[8];
  const float* bo = (const float*)d_in[9];
  float* out = (float*)d_out;

  char* ws = (char*)d_ws;
  unsigned short* xb  = (unsigned short*)(ws);
  unsigned short* wqb = (unsigned short*)(ws + 16777216);
  unsigned short* wkb = (unsigned short*)(ws + 18874368);
  unsigned short* wvb = (unsigned short*)(ws + 20971520);
  unsigned short* wob = (unsigned short*)(ws + 23068672);
  unsigned short* qb  = (unsigned short*)(ws + 25165824);
  unsigned short* kb  = (unsigned short*)(ws + 41943040);
  unsigned short* vtb = (unsigned short*)(ws + 58720256);
  unsigned short* aob = (unsigned short*)(ws + 75497472);

  cast_f32_bf16_x4<<<8192, 256, 0, stream>>>(x, xb, 2097152);
  cast_w4<<<dim3(1024, 4), 256, 0, stream>>>(wq, wk, wv, wo, wqb, wkb, wvb, wob);

  qkv_gemm<<<dim3(24, 64), 256, 0, stream>>>(xb, wqb, wkb, wvb, bq, bk, bv,
                                             qb, kb, vtb);
  attn_kernel<<<dim3(64, 8), 256, 0, stream>>>(qb, kb, vtb, aob);
  out_gemm<<<dim3(8, 64), 256, 0, stream>>>(aob, wob, bo, out);
}

// Round 7
// 185.934 us; speedup vs baseline: 1.0258x; 1.0258x over previous
//
#include <hip/hip_runtime.h>
#include <hip/hip_bf16.h>
#include <stdint.h>

typedef __attribute__((ext_vector_type(8))) short short8;
typedef __attribute__((ext_vector_type(4))) float f32x4;
typedef __attribute__((ext_vector_type(16))) float f32x16;

#define AS1 __attribute__((address_space(1)))
#define AS3 __attribute__((address_space(3)))

constexpr int Bc = 4, Sc = 2048, Dc = 1024, Hc = 16;

__device__ __forceinline__ unsigned short f2b(float x) {
  __hip_bfloat16 h = __float2bfloat16(x);
  return *reinterpret_cast<unsigned short*>(&h);
}

__device__ __forceinline__ uint32_t cvtpk(float lo, float hi) {
  uint32_t r;
  asm("v_cvt_pk_bf16_f32 %0, %1, %2" : "=v"(r) : "v"(lo), "v"(hi));
  return r;
}

// async global->LDS, 16B per lane; lds ptr must be wave-uniform (HW adds lane*16)
__device__ __forceinline__ void glds16(const void* g, void* l) {
  __builtin_amdgcn_global_load_lds((const AS1 uint32_t*)g, (AS3 uint32_t*)l, 16, 0, 0);
}

// ---------------------------------------------------------------- cast kernels
__global__ void cast_f32_bf16_x4(const float* __restrict__ in,
                                 unsigned short* __restrict__ out, int n4) {
  int i = blockIdx.x * blockDim.x + threadIdx.x;
  if (i >= n4) return;
  float4 a = ((const float4*)in)[i];
  ushort4 o;
  o.x = f2b(a.x); o.y = f2b(a.y); o.z = f2b(a.z); o.w = f2b(a.w);
  ((ushort4*)out)[i] = o;
}

// all four 1024x1024 weights in one launch: grid (1024, 4)
__global__ void cast_w4(const float* __restrict__ wq, const float* __restrict__ wk,
                        const float* __restrict__ wv, const float* __restrict__ wo,
                        unsigned short* __restrict__ oq, unsigned short* __restrict__ ok,
                        unsigned short* __restrict__ ov, unsigned short* __restrict__ oo) {
  int which = blockIdx.y;
  const float* in = which == 0 ? wq : which == 1 ? wk : which == 2 ? wv : wo;
  unsigned short* out = which == 0 ? oq : which == 1 ? ok : which == 2 ? ov : oo;
  int i = blockIdx.x * blockDim.x + threadIdx.x;
  float4 a = ((const float4*)in)[i];
  ushort4 o;
  o.x = f2b(a.x); o.y = f2b(a.y); o.z = f2b(a.z); o.w = f2b(a.w);
  ((ushort4*)out)[i] = o;
}

// ------------------------------------------------------- 128x128 GEMM core
// C[M,N] = A[M,K] * W[N,K]^T + bias;  K = N = 1024 fixed, tile 128x128, BK=32.
// Round-7 schedule: double-buffered LDS, K-loop unrolled x2 (compile-time buf
// -> static LDS addressing), incremental global pointers, counted vmcnt(4)
// (next tile's 4 loads stay in flight across compute), TWO barriers per tile:
//   STAGE(next) -> vmcnt(4) -> bar -> COMPUTE(cur) -> bar
// so stage-writes into a buffer always sit behind the barrier that closed
// that buffer's reads (round-6 single-barrier layout raced).
// Chunk-XOR swizzle slot = g ^ ((row>>1)&3) via pre-swizzled global source.
template<int MODE>
__device__ __forceinline__ void gemm128(
    const unsigned short* __restrict__ A, const unsigned short* __restrict__ W,
    const float* __restrict__ bias, void* __restrict__ outp,
    int m0, int n0, unsigned short (*lA)[128 * 32], unsigned short (*lB)[128 * 32])
{
  const int tid = threadIdx.x;
  const int w = tid >> 6, lane = tid & 63;
  const int g = lane >> 4, c = lane & 15;
  const int wr = w >> 1, wc = w & 1;

  f32x4 acc[4][4];
#pragma unroll
  for (int i = 0; i < 4; ++i)
#pragma unroll
    for (int j = 0; j < 4; ++j) acc[i][j] = f32x4{0.f, 0.f, 0.f, 0.f};

  const int srow = lane >> 2;                       // 0..15 local row
  const int gch = (lane & 3) ^ ((srow >> 1) & 3);   // pre-swizzled source chunk
  const int rslot = (g ^ ((c >> 1) & 3)) * 16;      // read-side byte slot

  // incremental per-lane global pointers (advance 32 elems per tile)
  const unsigned short* a0 = A + (size_t)(m0 + w * 16 + srow) * 1024 + gch * 8;
  const unsigned short* a1 = a0 + 64 * 1024;
  const unsigned short* b0 = W + (size_t)(n0 + w * 16 + srow) * 1024 + gch * 8;
  const unsigned short* b1 = b0 + 64 * 1024;

#define STAGE(buf)                                           \
  do {                                                       \
    glds16(a0, (char*)lA[buf] + w * 1024);                   \
    glds16(a1, (char*)lA[buf] + 4096 + w * 1024);            \
    glds16(b0, (char*)lB[buf] + w * 1024);                   \
    glds16(b1, (char*)lB[buf] + 4096 + w * 1024);            \
    a0 += 32; a1 += 32; b0 += 32; b1 += 32;                  \
  } while (0)

#define COMPUTE(buf)                                                          \
  do {                                                                        \
    short8 aF[4], bF[4];                                                      \
    _Pragma("unroll")                                                         \
    for (int mt = 0; mt < 4; ++mt)                                            \
      aF[mt] = *(const short8*)((const char*)lA[buf] +                        \
                 (wr * 64 + mt * 16 + c) * 64 + rslot);                       \
    _Pragma("unroll")                                                         \
    for (int nt = 0; nt < 4; ++nt)                                            \
      bF[nt] = *(const short8*)((const char*)lB[buf] +                        \
                 (wc * 64 + nt * 16 + c) * 64 + rslot);                       \
    _Pragma("unroll")                                                         \
    for (int mt = 0; mt < 4; ++mt)                                            \
      _Pragma("unroll")                                                       \
      for (int nt = 0; nt < 4; ++nt)                                          \
        acc[mt][nt] = __builtin_amdgcn_mfma_f32_16x16x32_bf16(                \
            aF[mt], bF[nt], acc[mt][nt], 0, 0, 0);                            \
  } while (0)

#define WAITC(n) asm volatile("s_waitcnt vmcnt(" #n ")" ::: "memory")
#define BAR                                      \
  do {                                           \
    __builtin_amdgcn_s_barrier();                \
    asm volatile("" ::: "memory");               \
  } while (0)

  STAGE(0);
  for (int t2 = 0; t2 < 32; t2 += 2) {
    // ---- tile t2 (buf0): stage t2+1 into buf1, wait t2's 4 loads only
    STAGE(1);
    WAITC(4);
    BAR;
    COMPUTE(0);
    BAR;                       // closes buf0 reads before next STAGE(0)
    // ---- tile t2+1 (buf1): stage t2+2 into buf0 if it exists
    if (t2 + 2 < 32) {
      STAGE(0);
      WAITC(4);
    } else {
      WAITC(0);
    }
    BAR;
    COMPUTE(1);
    BAR;                       // closes buf1 reads before next STAGE(1)
  }
#undef STAGE
#undef COMPUTE
#undef WAITC
#undef BAR

  // epilogue: C row = 4g+reg, col = c (per 16x16 tile)
#pragma unroll
  for (int mt = 0; mt < 4; ++mt) {
    int mg = m0 + wr * 64 + mt * 16 + 4 * g;
#pragma unroll
    for (int nt = 0; nt < 4; ++nt) {
      int ng = n0 + wc * 64 + nt * 16 + c;
      float bb_ = bias[ng];
      if constexpr (MODE == 0) {
        unsigned short* o = (unsigned short*)outp;
#pragma unroll
        for (int r = 0; r < 4; ++r)
          o[(size_t)(mg + r) * 1024 + ng] = f2b(acc[mt][nt][r] + bb_);
      } else if constexpr (MODE == 1) {
        unsigned short* o = (unsigned short*)outp;
        int bb = mg >> 11, s0 = mg & 2047;   // batch, seq (tile never crosses batch)
        int hh = ng >> 6, dd = ng & 63;      // head, depth
        ushort4 pk;
        pk.x = f2b(acc[mt][nt][0] + bb_);
        pk.y = f2b(acc[mt][nt][1] + bb_);
        pk.z = f2b(acc[mt][nt][2] + bb_);
        pk.w = f2b(acc[mt][nt][3] + bb_);
        *(ushort4*)&o[(((size_t)bb * Hc + hh) * 64 + dd) * Sc + s0] = pk;
      } else {
        float* o = (float*)outp;
#pragma unroll
        for (int r = 0; r < 4; ++r)
          o[(size_t)(mg + r) * 1024 + ng] = acc[mt][nt][r] + bb_;
      }
    }
  }
}

__global__ __launch_bounds__(256) void qkv_gemm(
    const unsigned short* __restrict__ xb,
    const unsigned short* __restrict__ wqb, const unsigned short* __restrict__ wkb,
    const unsigned short* __restrict__ wvb,
    const float* __restrict__ bq, const float* __restrict__ bk,
    const float* __restrict__ bv,
    unsigned short* __restrict__ qo, unsigned short* __restrict__ ko,
    unsigned short* __restrict__ vto)
{
  __shared__ unsigned short lA[2][128 * 32], lB[2][128 * 32];
  int which = blockIdx.x >> 3;
  int n0 = (blockIdx.x & 7) * 128;
  int m0 = blockIdx.y * 128;
  if (which == 0)      gemm128<0>(xb, wqb, bq, qo, m0, n0, lA, lB);
  else if (which == 1) gemm128<0>(xb, wkb, bk, ko, m0, n0, lA, lB);
  else                 gemm128<1>(xb, wvb, bv, vto, m0, n0, lA, lB);
}

__global__ __launch_bounds__(256) void out_gemm(
    const unsigned short* __restrict__ ao, const unsigned short* __restrict__ wob,
    const float* __restrict__ bo, float* __restrict__ out)
{
  __shared__ unsigned short lA[2][128 * 32], lB[2][128 * 32];
  gemm128<2>(ao, wob, bo, out, blockIdx.y * 128, blockIdx.x * 128, lA, lB);
}

// ----------------------------------------------------------- flash attention
// Paired q-tiles (qlo=y, qhi=15-y) sharing K/V staging; same-bh blocks on the
// same XCD. 32x32x16 MFMA, SWAPPED operands (T12): S^T = mfma(K,Q) so each
// lane owns one q-row (q = lane&31); softmax is in-lane + one shfl_xor(32).
// P^T stays in-register: cvt_pk -> xor-32 exchange -> B-operand of
// O^T = mfma(V^T, P^T). No P-LDS, no lgkm drains. LDS 32KB.
__global__ __launch_bounds__(256, 2) void attn_kernel(
    const unsigned short* __restrict__ qg, const unsigned short* __restrict__ kg,
    const unsigned short* __restrict__ vtg, unsigned short* __restrict__ ao)
{
  __shared__ unsigned short lK[2][64 * 64];
  __shared__ unsigned short lV[2][64 * 64];

  const int bh = blockIdx.x;
  const int qlo = blockIdx.y, qhi = 15 - qlo;
  const int b = bh >> 4, h = bh & 15;
  const int tid = threadIdx.x, w = tid >> 6, lane = tid & 63;
  const int qr = lane & 31, hi = lane >> 5;
  const int qb2[2] = { qlo * 128 + 32 * w, qhi * 128 + 32 * w };
  constexpr float CE = 0.125f * 1.44269504f;   // fold /sqrt(64) and log2(e)

  // Q as B-operand: col=q=qr, k(d) = 16i + 8hi + j
  short8 qB[2][4];
#pragma unroll
  for (int qi = 0; qi < 2; ++qi) {
    const unsigned short* qp = qg + (size_t)(b * Sc + qb2[qi] + qr) * Dc + h * 64 + 8 * hi;
#pragma unroll
    for (int i = 0; i < 4; ++i)
      qB[qi][i] = *(const short8*)(qp + 16 * i);
  }

  float m_[2] = { -3e38f, -3e38f }, lv[2] = { 0.f, 0.f };
  f32x16 oT[2][2];
#pragma unroll
  for (int qi = 0; qi < 2; ++qi)
#pragma unroll
    for (int n = 0; n < 2; ++n)
#pragma unroll
      for (int r = 0; r < 16; ++r) oT[qi][n][r] = 0.f;

  const int srow8 = lane >> 3;
  const int sslot = lane & 7;
  const unsigned short* kb_ = kg + (size_t)b * Sc * Dc + h * 64;
  const unsigned short* vb_ = vtg + (size_t)bh * 64 * Sc;

  auto stage = [&](int buf, int t) {
    const int kv0 = t * 64;
#pragma unroll
    for (int i = 0; i < 2; ++i) {
      int row = i * 32 + w * 8 + srow8;
      int gch = sslot ^ (row & 7);
      glds16(kb_ + (size_t)(kv0 + row) * Dc + gch * 8,
             (char*)lK[buf] + i * 4096 + w * 1024);
      glds16(vb_ + (size_t)row * Sc + kv0 + gch * 8,
             (char*)lV[buf] + i * 4096 + w * 1024);
    }
  };

  const int ntl = 2 * (qhi + 1);
  stage(0, 0);
  asm volatile("s_waitcnt vmcnt(0)" ::: "memory");
  __builtin_amdgcn_s_barrier();
  asm volatile("" ::: "memory");

  for (int t = 0; t < ntl; ++t) {
    const int cur = t & 1;
    const int kv0 = t * 64;
    if (t + 1 < ntl) stage(cur ^ 1, t + 1);

    if (kv0 <= qb2[1] + 31) {   // at least qhi active (wave-uniform)
      // K as A-operand (shared by both q-tiles): row=k-idx, d-chunk 2i+hi
      short8 kA[2][4];
#pragma unroll
      for (int kblk = 0; kblk < 2; ++kblk) {
        const int row = kblk * 32 + qr;
        const int swz = (row & 7) << 4;
#pragma unroll
        for (int i = 0; i < 4; ++i)
          kA[kblk][i] = *(const short8*)((const char*)lK[cur] + row * 128 +
                          (((2 * i + hi) * 16) ^ swz));
      }

      short8 pB[2][4];        // P^T B-frags per q-tile
      bool act[2];
#pragma unroll
      for (int qi = 0; qi < 2; ++qi) {
        const int qbase = qb2[qi];
        act[qi] = (kv0 <= qbase + 31);
        if (!act[qi]) continue;

        // ---- S^T = K Q (32k x 32q per block, 2 k-blocks)
        f32x16 sT[2];
        __builtin_amdgcn_s_setprio(1);
#pragma unroll
        for (int kblk = 0; kblk < 2; ++kblk) {
          f32x16 s;
#pragma unroll
          for (int r = 0; r < 16; ++r) s[r] = 0.f;
#pragma unroll
          for (int i = 0; i < 4; ++i)
            s = __builtin_amdgcn_mfma_f32_32x32x16_bf16(kA[kblk][i], qB[qi][i],
                                                        s, 0, 0, 0);
          sT[kblk] = s;
        }
        __builtin_amdgcn_s_setprio(0);

        // ---- causal mask (partial tiles only); q=qbase+qr, k from C-layout
        if (kv0 + 63 > qbase) {
          const int q = qbase + qr;
#pragma unroll
          for (int kblk = 0; kblk < 2; ++kblk)
#pragma unroll
            for (int r = 0; r < 16; ++r) {
              int k = kv0 + kblk * 32 + (r & 3) + 8 * (r >> 2) + 4 * hi;
              if (k > q) sT[kblk][r] = -1e30f;
            }
        }

        // ---- online softmax, in-lane + one xor-32 exchange
        float mx = sT[0][0];
#pragma unroll
        for (int r = 1; r < 16; ++r) mx = fmaxf(mx, sT[0][r]);
#pragma unroll
        for (int r = 0; r < 16; ++r) mx = fmaxf(mx, sT[1][r]);
        mx = fmaxf(mx, __shfl_xor(mx, 32));

        if (!__all(mx <= m_[qi] + 64.f)) {   // T13 defer-rescale (8 ln-units)
          const float mo = m_[qi];
          const float mn = fmaxf(mo, mx);
          const float sf = __builtin_amdgcn_exp2f((mo - mn) * CE);
          m_[qi] = mn;
          lv[qi] *= sf;
#pragma unroll
          for (int n = 0; n < 2; ++n)
#pragma unroll
            for (int r = 0; r < 16; ++r) oT[qi][n][r] *= sf;
        }
        const float mc = m_[qi] * CE;
        float ls = 0.f;
#pragma unroll
        for (int kblk = 0; kblk < 2; ++kblk)
#pragma unroll
          for (int r = 0; r < 16; ++r) {
            float p = __builtin_amdgcn_exp2f(sT[kblk][r] * CE - mc);
            sT[kblk][r] = p;
            ls += p;
          }
        lv[qi] += ls;    // per-lane partial; xor-32 reduce at end

        // ---- P^T -> bf16 B-frags, in-register exchange across xor-32
#pragma unroll
        for (int kblk = 0; kblk < 2; ++kblk) {
          uint32_t pk[4][2];
#pragma unroll
          for (int qp = 0; qp < 4; ++qp)
#pragma unroll
            for (int rp = 0; rp < 2; ++rp)
              pk[qp][rp] = cvtpk(sT[kblk][4 * qp + 2 * rp],
                                 sT[kblk][4 * qp + 2 * rp + 1]);
#pragma unroll
          for (int m2 = 0; m2 < 2; ++m2) {
            uint32_t s0 = hi ? pk[2 * m2][0] : pk[2 * m2 + 1][0];
            uint32_t s1 = hi ? pk[2 * m2][1] : pk[2 * m2 + 1][1];
            uint32_t r0 = __shfl_xor(s0, 32);
            uint32_t r1 = __shfl_xor(s1, 32);
            uint32_t w0 = hi ? r0 : pk[2 * m2][0];
            uint32_t w1 = hi ? r1 : pk[2 * m2][1];
            uint32_t w2 = hi ? pk[2 * m2 + 1][0] : r0;
            uint32_t w3 = hi ? pk[2 * m2 + 1][1] : r1;
            uint32_t tmp[4] = { w0, w1, w2, w3 };
            pB[qi][2 * kblk + m2] = *(const short8*)tmp;
          }
        }
      }

      // V^T as A-operand (shared): row=d, kv-chunk 2m+hi
      short8 vA[2][4];
#pragma unroll
      for (int n = 0; n < 2; ++n) {
        const int row = 32 * n + qr;
        const int swz = (row & 7) << 4;
#pragma unroll
        for (int m = 0; m < 4; ++m)
          vA[n][m] = *(const short8*)((const char*)lV[cur] + row * 128 +
                       (((2 * m + hi) * 16) ^ swz));
      }

      // ---- O^T += V^T P^T
      __builtin_amdgcn_s_setprio(1);
#pragma unroll
      for (int qi = 0; qi < 2; ++qi) {
        if (!act[qi]) continue;
#pragma unroll
        for (int n = 0; n < 2; ++n)
#pragma unroll
          for (int m = 0; m < 4; ++m)
            oT[qi][n] = __builtin_amdgcn_mfma_f32_32x32x16_bf16(
                vA[n][m], pB[qi][m], oT[qi][n], 0, 0, 0);
      }
      __builtin_amdgcn_s_setprio(0);
    }

    asm volatile("s_waitcnt vmcnt(0)" ::: "memory");
    __builtin_amdgcn_s_barrier();
    asm volatile("" ::: "memory");
  }

  // ---- finalize: full row-sum via xor-32, normalize, packed store
#pragma unroll
  for (int qi = 0; qi < 2; ++qi) {
    float l = lv[qi] + __shfl_xor(lv[qi], 32);
    float inv = 1.0f / l;
    const int qrow = qb2[qi] + qr;
    unsigned short* op = ao + (size_t)(b * Sc + qrow) * Dc + h * 64;
#pragma unroll
    for (int n = 0; n < 2; ++n)
#pragma unroll
      for (int rg = 0; rg < 4; ++rg) {
        ushort4 pkv;
        pkv.x = f2b(oT[qi][n][4 * rg + 0] * inv);
        pkv.y = f2b(oT[qi][n][4 * rg + 1] * inv);
        pkv.z = f2b(oT[qi][n][4 * rg + 2] * inv);
        pkv.w = f2b(oT[qi][n][4 * rg + 3] * inv);
        *(ushort4*)(op + 32 * n + 8 * rg + 4 * hi) = pkv;
      }
  }
}

// ------------------------------------------------------------------- launch
extern "C" void kernel_launch(void* const* d_in, const int* in_sizes, int n_in,
                              void* d_out, int out_size, void* d_ws, size_t ws_size,
                              hipStream_t stream) {
  const float* x  = (const float*)d_in[0];
  // d_in[1] = mask: causal triu(k=1), applied analytically in attn_kernel
  const float* wq = (const float*)d_in[2];
  const float* bq = (const float*)d_in[3];
  const float* wk = (const float*)d_in[4];
  const float* bk = (const float*)d_in[5];
  const float* wv = (const float*)d_in[6];
  const float* bv = (const float*)d_in[7];
  const float* wo = (const float*)d_in[8];
  const float* bo = (const float*)d_in[9];
  float* out = (float*)d_out;

  char* ws = (char*)d_ws;
  unsigned short* xb  = (unsigned short*)(ws);
  unsigned short* wqb = (unsigned short*)(ws + 16777216);
  unsigned short* wkb = (unsigned short*)(ws + 18874368);
  unsigned short* wvb = (unsigned short*)(ws + 20971520);
  unsigned short* wob = (unsigned short*)(ws + 23068672);
  unsigned short* qb  = (unsigned short*)(ws + 25165824);
  unsigned short* kb  = (unsigned short*)(ws + 41943040);
  unsigned short* vtb = (unsigned short*)(ws + 58720256);
  unsigned short* aob = (unsigned short*)(ws + 75497472);

  cast_f32_bf16_x4<<<8192, 256, 0, stream>>>(x, xb, 2097152);
  cast_w4<<<dim3(1024, 4), 256, 0, stream>>>(wq, wk, wv, wo, wqb, wkb, wvb, wob);

  qkv_gemm<<<dim3(24, 64), 256, 0, stream>>>(xb, wqb, wkb, wvb, bq, bk, bv,
                                             qb, kb, vtb);
  attn_kernel<<<dim3(64, 8), 256, 0, stream>>>(qb, kb, vtb, aob);
  out_gemm<<<dim3(8, 64), 256, 0, stream>>>(aob, wob, bo, out);
}

// Round 8
// 161.398 us; speedup vs baseline: 1.1818x; 1.1520x over previous
//
#include <hip/hip_runtime.h>
#include <hip/hip_bf16.h>
#include <stdint.h>

typedef __attribute__((ext_vector_type(8))) short short8;
typedef __attribute__((ext_vector_type(4))) float f32x4;
typedef __attribute__((ext_vector_type(16))) float f32x16;

#define AS1 __attribute__((address_space(1)))
#define AS3 __attribute__((address_space(3)))

constexpr int Bc = 4, Sc = 2048, Dc = 1024, Hc = 16;

__device__ __forceinline__ unsigned short f2b(float x) {
  __hip_bfloat16 h = __float2bfloat16(x);
  return *reinterpret_cast<unsigned short*>(&h);
}

__device__ __forceinline__ uint32_t cvtpk(float lo, float hi) {
  uint32_t r;
  asm("v_cvt_pk_bf16_f32 %0, %1, %2" : "=v"(r) : "v"(lo), "v"(hi));
  return r;
}

// async global->LDS, 16B per lane; lds ptr must be wave-uniform (HW adds lane*16)
__device__ __forceinline__ void glds16(const void* g, void* l) {
  __builtin_amdgcn_global_load_lds((const AS1 uint32_t*)g, (AS3 uint32_t*)l, 16, 0, 0);
}

// ---------------------------------------------------------------- cast kernels
__global__ void cast_f32_bf16_x4(const float* __restrict__ in,
                                 unsigned short* __restrict__ out, int n4) {
  int i = blockIdx.x * blockDim.x + threadIdx.x;
  if (i >= n4) return;
  float4 a = ((const float4*)in)[i];
  ushort4 o;
  o.x = f2b(a.x); o.y = f2b(a.y); o.z = f2b(a.z); o.w = f2b(a.w);
  ((ushort4*)out)[i] = o;
}

// all four 1024x1024 weights in one launch: grid (1024, 4)
__global__ void cast_w4(const float* __restrict__ wq, const float* __restrict__ wk,
                        const float* __restrict__ wv, const float* __restrict__ wo,
                        unsigned short* __restrict__ oq, unsigned short* __restrict__ ok,
                        unsigned short* __restrict__ ov, unsigned short* __restrict__ oo) {
  int which = blockIdx.y;
  const float* in = which == 0 ? wq : which == 1 ? wk : which == 2 ? wv : wo;
  unsigned short* out = which == 0 ? oq : which == 1 ? ok : which == 2 ? ov : oo;
  int i = blockIdx.x * blockDim.x + threadIdx.x;
  float4 a = ((const float4*)in)[i];
  ushort4 o;
  o.x = f2b(a.x); o.y = f2b(a.y); o.z = f2b(a.z); o.w = f2b(a.w);
  ((ushort4*)out)[i] = o;
}

// ------------------------------------------------------- 128x128 GEMM core
// C[M,N] = A[M,K] * W[N,K]^T + bias;  K = N = 1024 fixed, tile 128x128, BK=64.
// Round-4 proven schedule (single buffer): STAGE -> vmcnt(0)+bar -> COMPUTE
// -> bar. BK=64 halves the drain/barrier event count vs BK=32. Rows are now
// 128B, so fragment reads REQUIRE the chunk-XOR swizzle slot ^= (row&7),
// applied on the global source (stage) and the ds_read address (rule 21):
// gives exactly 8 lanes per 16B slot-group = conflict-free b128.
template<int MODE>
__device__ __forceinline__ void gemm128(
    const unsigned short* __restrict__ A, const unsigned short* __restrict__ W,
    const float* __restrict__ bias, void* __restrict__ outp,
    int m0, int n0, unsigned short* lA, unsigned short* lB)
{
  const int tid = threadIdx.x;
  const int w = tid >> 6, lane = tid & 63;
  const int g = lane >> 4, c = lane & 15;
  const int wr = w >> 1, wc = w & 1;

  f32x4 acc[4][4];
#pragma unroll
  for (int i = 0; i < 4; ++i)
#pragma unroll
    for (int j = 0; j < 4; ++j) acc[i][j] = f32x4{0.f, 0.f, 0.f, 0.f};

  const int lrow8 = lane >> 3;            // 0..7: row within 8-row stage stripe
  const int gslot = (lane & 7) ^ lrow8;   // pre-swizzled 16B chunk in 64-elem row

  // per-lane global pointers, one per stage-round j (rows (j*4+w)*8 + lrow8)
  const unsigned short* ap[4];
  const unsigned short* bp[4];
#pragma unroll
  for (int j = 0; j < 4; ++j) {
    int row = (j * 4 + w) * 8 + lrow8;
    ap[j] = A + (size_t)(m0 + row) * 1024 + gslot * 8;
    bp[j] = W + (size_t)(n0 + row) * 1024 + gslot * 8;
  }

  // read-side swizzled byte slots (row&7 == c&7 for all fragment rows)
  const int sl0 = (g ^ (c & 7)) << 4;        // ks=0 chunk (g)
  const int sl1 = ((4 ^ g) ^ (c & 7)) << 4;  // ks=1 chunk (4+g)
  const char* lA0 = (const char*)lA + (wr * 64 + c) * 128 + sl0;
  const char* lA1 = (const char*)lA + (wr * 64 + c) * 128 + sl1;
  const char* lB0 = (const char*)lB + (wc * 64 + c) * 128 + sl0;
  const char* lB1 = (const char*)lB + (wc * 64 + c) * 128 + sl1;

#define STAGE                                               \
  do {                                                      \
    _Pragma("unroll")                                       \
    for (int j = 0; j < 4; ++j) {                           \
      glds16(ap[j], (char*)lA + (j * 4 + w) * 1024);        \
      glds16(bp[j], (char*)lB + (j * 4 + w) * 1024);        \
      ap[j] += 64; bp[j] += 64;                             \
    }                                                       \
  } while (0)

  STAGE;
  for (int t = 0; t < 16; ++t) {
    asm volatile("s_waitcnt vmcnt(0)" ::: "memory");
    __builtin_amdgcn_s_barrier();
    asm volatile("" ::: "memory");

#pragma unroll
    for (int ks = 0; ks < 2; ++ks) {
      short8 aF[4], bF[4];
#pragma unroll
      for (int mt = 0; mt < 4; ++mt)
        aF[mt] = *(const short8*)((ks ? lA1 : lA0) + mt * 2048);
#pragma unroll
      for (int nt = 0; nt < 4; ++nt)
        bF[nt] = *(const short8*)((ks ? lB1 : lB0) + nt * 2048);
#pragma unroll
      for (int mt = 0; mt < 4; ++mt)
#pragma unroll
        for (int nt = 0; nt < 4; ++nt)
          acc[mt][nt] = __builtin_amdgcn_mfma_f32_16x16x32_bf16(
              aF[mt], bF[nt], acc[mt][nt], 0, 0, 0);
    }
    asm volatile("" ::: "memory");
    __builtin_amdgcn_s_barrier();
    asm volatile("" ::: "memory");
    if (t + 1 < 16) STAGE;
  }
#undef STAGE

  // epilogue: C row = 4g+reg, col = c (per 16x16 tile)
#pragma unroll
  for (int mt = 0; mt < 4; ++mt) {
    int mg = m0 + wr * 64 + mt * 16 + 4 * g;
#pragma unroll
    for (int nt = 0; nt < 4; ++nt) {
      int ng = n0 + wc * 64 + nt * 16 + c;
      float bb_ = bias[ng];
      if constexpr (MODE == 0) {
        unsigned short* o = (unsigned short*)outp;
#pragma unroll
        for (int r = 0; r < 4; ++r)
          o[(size_t)(mg + r) * 1024 + ng] = f2b(acc[mt][nt][r] + bb_);
      } else if constexpr (MODE == 1) {
        unsigned short* o = (unsigned short*)outp;
        int bb = mg >> 11, s0 = mg & 2047;   // batch, seq (tile never crosses batch)
        int hh = ng >> 6, dd = ng & 63;      // head, depth
        ushort4 pk;
        pk.x = f2b(acc[mt][nt][0] + bb_);
        pk.y = f2b(acc[mt][nt][1] + bb_);
        pk.z = f2b(acc[mt][nt][2] + bb_);
        pk.w = f2b(acc[mt][nt][3] + bb_);
        *(ushort4*)&o[(((size_t)bb * Hc + hh) * 64 + dd) * Sc + s0] = pk;
      } else {
        float* o = (float*)outp;
#pragma unroll
        for (int r = 0; r < 4; ++r)
          o[(size_t)(mg + r) * 1024 + ng] = acc[mt][nt][r] + bb_;
      }
    }
  }
}

// grid (64, 24): x = m-tile so all 24 n/which-blocks of one m-tile land on the
// same XCD (linear id % 8 == x % 8) -> A-tile fetched into one L2, not eight.
__global__ __launch_bounds__(256) void qkv_gemm(
    const unsigned short* __restrict__ xb,
    const unsigned short* __restrict__ wqb, const unsigned short* __restrict__ wkb,
    const unsigned short* __restrict__ wvb,
    const float* __restrict__ bq, const float* __restrict__ bk,
    const float* __restrict__ bv,
    unsigned short* __restrict__ qo, unsigned short* __restrict__ ko,
    unsigned short* __restrict__ vto)
{
  __shared__ unsigned short lA[128 * 64], lB[128 * 64];
  int m0 = blockIdx.x * 128;
  int which = blockIdx.y >> 3;
  int n0 = (blockIdx.y & 7) * 128;
  if (which == 0)      gemm128<0>(xb, wqb, bq, qo, m0, n0, lA, lB);
  else if (which == 1) gemm128<0>(xb, wkb, bk, ko, m0, n0, lA, lB);
  else                 gemm128<1>(xb, wvb, bv, vto, m0, n0, lA, lB);
}

// grid (64, 8): x = m-tile (same-XCD A sharing)
__global__ __launch_bounds__(256) void out_gemm(
    const unsigned short* __restrict__ ao, const unsigned short* __restrict__ wob,
    const float* __restrict__ bo, float* __restrict__ out)
{
  __shared__ unsigned short lA[128 * 64], lB[128 * 64];
  gemm128<2>(ao, wob, bo, out, blockIdx.x * 128, blockIdx.y * 128, lA, lB);
}

// ----------------------------------------------------------- flash attention
// Paired q-tiles (qlo=y, qhi=15-y) sharing K/V staging; same-bh blocks on the
// same XCD. 32x32x16 MFMA, SWAPPED operands (T12): S^T = mfma(K,Q) so each
// lane owns one q-row (q = lane&31); softmax is in-lane + one shfl_xor(32).
// P^T stays in-register: cvt_pk -> xor-32 exchange -> B-operand of
// O^T = mfma(V^T, P^T). No P-LDS, no lgkm drains. LDS 32KB.
__global__ __launch_bounds__(256, 2) void attn_kernel(
    const unsigned short* __restrict__ qg, const unsigned short* __restrict__ kg,
    const unsigned short* __restrict__ vtg, unsigned short* __restrict__ ao)
{
  __shared__ unsigned short lK[2][64 * 64];
  __shared__ unsigned short lV[2][64 * 64];

  const int bh = blockIdx.x;
  const int qlo = blockIdx.y, qhi = 15 - qlo;
  const int b = bh >> 4, h = bh & 15;
  const int tid = threadIdx.x, w = tid >> 6, lane = tid & 63;
  const int qr = lane & 31, hi = lane >> 5;
  const int qb2[2] = { qlo * 128 + 32 * w, qhi * 128 + 32 * w };
  constexpr float CE = 0.125f * 1.44269504f;   // fold /sqrt(64) and log2(e)

  // Q as B-operand: col=q=qr, k(d) = 16i + 8hi + j
  short8 qB[2][4];
#pragma unroll
  for (int qi = 0; qi < 2; ++qi) {
    const unsigned short* qp = qg + (size_t)(b * Sc + qb2[qi] + qr) * Dc + h * 64 + 8 * hi;
#pragma unroll
    for (int i = 0; i < 4; ++i)
      qB[qi][i] = *(const short8*)(qp + 16 * i);
  }

  float m_[2] = { -3e38f, -3e38f }, lv[2] = { 0.f, 0.f };
  f32x16 oT[2][2];
#pragma unroll
  for (int qi = 0; qi < 2; ++qi)
#pragma unroll
    for (int n = 0; n < 2; ++n)
#pragma unroll
      for (int r = 0; r < 16; ++r) oT[qi][n][r] = 0.f;

  const int srow8 = lane >> 3;
  const int sslot = lane & 7;
  const unsigned short* kb_ = kg + (size_t)b * Sc * Dc + h * 64;
  const unsigned short* vb_ = vtg + (size_t)bh * 64 * Sc;

  auto stage = [&](int buf, int t) {
    const int kv0 = t * 64;
#pragma unroll
    for (int i = 0; i < 2; ++i) {
      int row = i * 32 + w * 8 + srow8;
      int gch = sslot ^ (row & 7);
      glds16(kb_ + (size_t)(kv0 + row) * Dc + gch * 8,
             (char*)lK[buf] + i * 4096 + w * 1024);
      glds16(vb_ + (size_t)row * Sc + kv0 + gch * 8,
             (char*)lV[buf] + i * 4096 + w * 1024);
    }
  };

  const int ntl = 2 * (qhi + 1);
  stage(0, 0);
  asm volatile("s_waitcnt vmcnt(0)" ::: "memory");
  __builtin_amdgcn_s_barrier();
  asm volatile("" ::: "memory");

  for (int t = 0; t < ntl; ++t) {
    const int cur = t & 1;
    const int kv0 = t * 64;
    if (t + 1 < ntl) stage(cur ^ 1, t + 1);

    if (kv0 <= qb2[1] + 31) {   // at least qhi active (wave-uniform)
      // K as A-operand (shared by both q-tiles): row=k-idx, d-chunk 2i+hi
      short8 kA[2][4];
#pragma unroll
      for (int kblk = 0; kblk < 2; ++kblk) {
        const int row = kblk * 32 + qr;
        const int swz = (row & 7) << 4;
#pragma unroll
        for (int i = 0; i < 4; ++i)
          kA[kblk][i] = *(const short8*)((const char*)lK[cur] + row * 128 +
                          (((2 * i + hi) * 16) ^ swz));
      }

      short8 pB[2][4];        // P^T B-frags per q-tile
      bool act[2];
#pragma unroll
      for (int qi = 0; qi < 2; ++qi) {
        const int qbase = qb2[qi];
        act[qi] = (kv0 <= qbase + 31);
        if (!act[qi]) continue;

        // ---- S^T = K Q (32k x 32q per block, 2 k-blocks)
        f32x16 sT[2];
        __builtin_amdgcn_s_setprio(1);
#pragma unroll
        for (int kblk = 0; kblk < 2; ++kblk) {
          f32x16 s;
#pragma unroll
          for (int r = 0; r < 16; ++r) s[r] = 0.f;
#pragma unroll
          for (int i = 0; i < 4; ++i)
            s = __builtin_amdgcn_mfma_f32_32x32x16_bf16(kA[kblk][i], qB[qi][i],
                                                        s, 0, 0, 0);
          sT[kblk] = s;
        }
        __builtin_amdgcn_s_setprio(0);

        // ---- causal mask (partial tiles only); q=qbase+qr, k from C-layout
        if (kv0 + 63 > qbase) {
          const int q = qbase + qr;
#pragma unroll
          for (int kblk = 0; kblk < 2; ++kblk)
#pragma unroll
            for (int r = 0; r < 16; ++r) {
              int k = kv0 + kblk * 32 + (r & 3) + 8 * (r >> 2) + 4 * hi;
              if (k > q) sT[kblk][r] = -1e30f;
            }
        }

        // ---- online softmax, in-lane + one xor-32 exchange
        float mx = sT[0][0];
#pragma unroll
        for (int r = 1; r < 16; ++r) mx = fmaxf(mx, sT[0][r]);
#pragma unroll
        for (int r = 0; r < 16; ++r) mx = fmaxf(mx, sT[1][r]);
        mx = fmaxf(mx, __shfl_xor(mx, 32));

        if (!__all(mx <= m_[qi] + 64.f)) {   // T13 defer-rescale (8 ln-units)
          const float mo = m_[qi];
          const float mn = fmaxf(mo, mx);
          const float sf = __builtin_amdgcn_exp2f((mo - mn) * CE);
          m_[qi] = mn;
          lv[qi] *= sf;
#pragma unroll
          for (int n = 0; n < 2; ++n)
#pragma unroll
            for (int r = 0; r < 16; ++r) oT[qi][n][r] *= sf;
        }
        const float mc = m_[qi] * CE;
        float ls = 0.f;
#pragma unroll
        for (int kblk = 0; kblk < 2; ++kblk)
#pragma unroll
          for (int r = 0; r < 16; ++r) {
            float p = __builtin_amdgcn_exp2f(sT[kblk][r] * CE - mc);
            sT[kblk][r] = p;
            ls += p;
          }
        lv[qi] += ls;    // per-lane partial; xor-32 reduce at end

        // ---- P^T -> bf16 B-frags, in-register exchange across xor-32
#pragma unroll
        for (int kblk = 0; kblk < 2; ++kblk) {
          uint32_t pk[4][2];
#pragma unroll
          for (int qp = 0; qp < 4; ++qp)
#pragma unroll
            for (int rp = 0; rp < 2; ++rp)
              pk[qp][rp] = cvtpk(sT[kblk][4 * qp + 2 * rp],
                                 sT[kblk][4 * qp + 2 * rp + 1]);
#pragma unroll
          for (int m2 = 0; m2 < 2; ++m2) {
            uint32_t s0 = hi ? pk[2 * m2][0] : pk[2 * m2 + 1][0];
            uint32_t s1 = hi ? pk[2 * m2][1] : pk[2 * m2 + 1][1];
            uint32_t r0 = __shfl_xor(s0, 32);
            uint32_t r1 = __shfl_xor(s1, 32);
            uint32_t w0 = hi ? r0 : pk[2 * m2][0];
            uint32_t w1 = hi ? r1 : pk[2 * m2][1];
            uint32_t w2 = hi ? pk[2 * m2 + 1][0] : r0;
            uint32_t w3 = hi ? pk[2 * m2 + 1][1] : r1;
            uint32_t tmp[4] = { w0, w1, w2, w3 };
            pB[qi][2 * kblk + m2] = *(const short8*)tmp;
          }
        }
      }

      // V^T as A-operand (shared): row=d, kv-chunk 2m+hi
      short8 vA[2][4];
#pragma unroll
      for (int n = 0; n < 2; ++n) {
        const int row = 32 * n + qr;
        const int swz = (row & 7) << 4;
#pragma unroll
        for (int m = 0; m < 4; ++m)
          vA[n][m] = *(const short8*)((const char*)lV[cur] + row * 128 +
                       (((2 * m + hi) * 16) ^ swz));
      }

      // ---- O^T += V^T P^T
      __builtin_amdgcn_s_setprio(1);
#pragma unroll
      for (int qi = 0; qi < 2; ++qi) {
        if (!act[qi]) continue;
#pragma unroll
        for (int n = 0; n < 2; ++n)
#pragma unroll
          for (int m = 0; m < 4; ++m)
            oT[qi][n] = __builtin_amdgcn_mfma_f32_32x32x16_bf16(
                vA[n][m], pB[qi][m], oT[qi][n], 0, 0, 0);
      }
      __builtin_amdgcn_s_setprio(0);
    }

    asm volatile("s_waitcnt vmcnt(0)" ::: "memory");
    __builtin_amdgcn_s_barrier();
    asm volatile("" ::: "memory");
  }

  // ---- finalize: full row-sum via xor-32, normalize, packed store
#pragma unroll
  for (int qi = 0; qi < 2; ++qi) {
    float l = lv[qi] + __shfl_xor(lv[qi], 32);
    float inv = 1.0f / l;
    const int qrow = qb2[qi] + qr;
    unsigned short* op = ao + (size_t)(b * Sc + qrow) * Dc + h * 64;
#pragma unroll
    for (int n = 0; n < 2; ++n)
#pragma unroll
      for (int rg = 0; rg < 4; ++rg) {
        ushort4 pkv;
        pkv.x = f2b(oT[qi][n][4 * rg + 0] * inv);
        pkv.y = f2b(oT[qi][n][4 * rg + 1] * inv);
        pkv.z = f2b(oT[qi][n][4 * rg + 2] * inv);
        pkv.w = f2b(oT[qi][n][4 * rg + 3] * inv);
        *(ushort4*)(op + 32 * n + 8 * rg + 4 * hi) = pkv;
      }
  }
}

// ------------------------------------------------------------------- launch
extern "C" void kernel_launch(void* const* d_in, const int* in_sizes, int n_in,
                              void* d_out, int out_size, void* d_ws, size_t ws_size,
                              hipStream_t stream) {
  const float* x  = (const float*)d_in[0];
  // d_in[1] = mask: causal triu(k=1), applied analytically in attn_kernel
  const float* wq = (const float*)d_in[2];
  const float* bq = (const float*)d_in[3];
  const float* wk = (const float*)d_in[4];
  const float* bk = (const float*)d_in[5];
  const float* wv = (const float*)d_in[6];
  const float* bv = (const float*)d_in[7];
  const float* wo = (const float*)d_in[8];
  const float* bo = (const float*)d_in[9];
  float* out = (float*)d_out;

  char* ws = (char*)d_ws;
  unsigned short* xb  = (unsigned short*)(ws);
  unsigned short* wqb = (unsigned short*)(ws + 16777216);
  unsigned short* wkb = (unsigned short*)(ws + 18874368);
  unsigned short* wvb = (unsigned short*)(ws + 20971520);
  unsigned short* wob = (unsigned short*)(ws + 23068672);
  unsigned short* qb  = (unsigned short*)(ws + 25165824);
  unsigned short* kb  = (unsigned short*)(ws + 41943040);
  unsigned short* vtb = (unsigned short*)(ws + 58720256);
  unsigned short* aob = (unsigned short*)(ws + 75497472);

  cast_f32_bf16_x4<<<8192, 256, 0, stream>>>(x, xb, 2097152);
  cast_w4<<<dim3(1024, 4), 256, 0, stream>>>(wq, wk, wv, wo, wqb, wkb, wvb, wob);

  qkv_gemm<<<dim3(64, 24), 256, 0, stream>>>(xb, wqb, wkb, wvb, bq, bk, bv,
                                             qb, kb, vtb);
  attn_kernel<<<dim3(64, 8), 256, 0, stream>>>(qb, kb, vtb, aob);
  out_gemm<<<dim3(64, 8), 256, 0, stream>>>(aob, wob, bo, out);
}